// Round 8
// baseline (98.521 us; speedup 1.0000x reference)
//
#include <hip/hip_runtime.h>
#include <hip/hip_bf16.h>

#define EPSW 1e-6f

typedef __attribute__((ext_vector_type(4))) float floatx4;
typedef __attribute__((ext_vector_type(4))) unsigned int uintx4;
typedef __attribute__((ext_vector_type(8))) short shortx8;   // 8 bf16 (4 VGPRs)

// round-to-nearest-even float -> bf16 bits (finite inputs)
__device__ __forceinline__ unsigned short f2bf(float f) {
    unsigned int u = __float_as_uint(f);
    u = (u + 0x7fffu + ((u >> 16) & 1u)) >> 16;
    return (unsigned short)u;
}

__device__ __forceinline__ unsigned int pk2(float lo, float hi) {
    return (unsigned int)f2bf(lo) | ((unsigned int)f2bf(hi) << 16);
}

// pack 8 fp32 -> bf16 MFMA fragment (shortx8)
__device__ __forceinline__ shortx8 pk8s(floatx4 a, floatx4 b) {
    union { uintx4 u; shortx8 s; } r;
    r.u.x = pk2(a.x, a.y); r.u.y = pk2(a.z, a.w);
    r.u.z = pk2(b.x, b.y); r.u.w = pk2(b.z, b.w);
    return r.s;
}

// ---------------------------------------------------------------------------
// mbuild: 4 blocks x 256 threads. Mt[c][n] = (A@A)[n][c], 16 n-rows/block.
// Separate (tiny) kernel so the kernel boundary orders Mt before gcn_fused
// reads it -- no fences (r3 lesson: device-scope fences cost more than a
// launch). Numerics identical to r5/r7 proven code.
// ---------------------------------------------------------------------------
__global__ __launch_bounds__(256) void mbuild(const int* __restrict__ ei,
                                              const float* __restrict__ ew,
                                              float* __restrict__ Mt) {
    __shared__ float sA[4224];                 // A 4096 | deg 64 | dinv 64
    const int bm = blockIdx.x;                 // n-slice [bm*16, bm*16+16)
    const int t  = threadIdx.x;
    float* A    = sA;
    float* deg  = A + 4096;
    float* dinv = deg + 64;
    if (t < 64) deg[t] = 1.0f;                 // self-loop pre-added
    for (int i = t; i < 4096; i += 256) A[i] = 0.0f;
    __syncthreads();
    const int* srcp = ei;
    const int* dstp = ei + 4096;
#pragma unroll
    for (int i = 0; i < 16; ++i) {
        const int e = i * 256 + t;
        float w = ew[e];
        w = (w <= 0.0f) ? EPSW : w;
        atomicAdd(&deg[dstp[e]], w);
    }
    __syncthreads();
    if (t < 64) dinv[t] = 1.0f / sqrtf(deg[t]);
    __syncthreads();
#pragma unroll
    for (int i = 0; i < 16; ++i) {
        const int e = i * 256 + t;
        float w = ew[e];
        w = (w <= 0.0f) ? EPSW : w;
        const int s = srcp[e], d = dstp[e];
        atomicAdd(&A[d * 64 + s], dinv[s] * w * dinv[d]);
    }
    if (t < 64) atomicAdd(&A[t * 64 + t], dinv[t] * dinv[t]);
    __syncthreads();
    const int c  = t & 63;
    const int rr = t >> 6;                     // 0..3 (wave-uniform)
    float s0 = 0.f, s1 = 0.f, s2 = 0.f, s3 = 0.f;
#pragma unroll 8
    for (int k = 0; k < 64; ++k) {
        const float akc = A[k * 64 + c];
        const float* an = A + (bm * 16 + rr * 4) * 64 + k;
        s0 += an[0]   * akc;
        s1 += an[64]  * akc;
        s2 += an[128] * akc;
        s3 += an[192] * akc;
    }
    float* mo = Mt + c * 64 + bm * 16 + rr * 4;
    mo[0] = s0; mo[1] = s1; mo[2] = s2; mo[3] = s3;
}

// ---------------------------------------------------------------------------
// gcn_fused: 256 blocks x 512 threads (8 waves). H-SPLIT, FULL-K:
//   bid = hs*32 + batch  (hs = bid>>5: 16-wide h-slice; batch = bid&31).
//   bid%8 = batch%8 -> all 8 h-blocks of a batch share one XCD (round-robin
//   dispatch), so the batch's x rows (512 KB) and W (1 MB) stay L2-resident:
//   per-XCD footprint = 4 batches x 512 KB + W 1 MB = 3 MB < 4 MB L2.
// Block computes z(64 nodes x 16 h) over FULL K=2000 -> complete (no K-split
// partials, no zp round-trip, no apply_M kernel), then finishes
// y = bias + M@z in-block (r4-proven fp32 VALU loop).
// K-loop: 64 chunks of 32 k, wave w owns chunks c == w (mod 8) -> x read
// exactly once per block. Fragments load DIRECT global->reg in MFMA layout
// (lane m=lane&15 row, q=lane>>4 k-group; per chunk per thread: x 4rt x 32 B
// + W 32 B = 10 float4), fp32->bf16 in-register (pk8s), 2-deep prefetch via
// 3 register sets (full unroll -> compile-time indexing, no scratch).
// No LDS, no barriers in the K-loop; 8 waves slip freely.
// Epilogue: zpart[8][64][17] LDS (+17 pad), 8-way reduce, M-apply, store y.
// ---------------------------------------------------------------------------
__global__ __launch_bounds__(512) void gcn_fused(
        const float* __restrict__ x,
        const float* __restrict__ W,
        const float* __restrict__ Mtg,
        const float* __restrict__ bias,
        float* __restrict__ y) {
    __shared__ __align__(16) float lds[8 * 1088 + 1088 + 4096];  // ~55.6 KB
    float* zpart = lds;                 // [8][64][17]
    float* zs    = lds + 8 * 1088;      // [64][17]
    float* Ms    = zs + 1088;           // [4096]

    const int t     = threadIdx.x;
    const int bid   = blockIdx.x;
    const int hs    = bid >> 5;         // 0..7
    const int batch = bid & 31;
    const int rbase = batch * 64;
    const int hbase = hs * 16;

    const int wave = t >> 6, lane = t & 63;
    const int m = lane & 15, q = lane >> 4;

    const float* xr0 = x + (size_t)(rbase + m) * 2000;       // +rt*32000
    const float* wr  = W + (size_t)(hbase + m) * 2000;

    floatx4 acc[4];
#pragma unroll
    for (int rt = 0; rt < 4; ++rt) acc[rt] = (floatx4){0.f, 0.f, 0.f, 0.f};

    // 3 staging sets -> 2 chunks in flight while one converts/MFMAs
    floatx4 fA[3][4][2];
    floatx4 fB[3][2];

#define LOADK(i_)                                                             \
    {                                                                         \
        const int s_ = (i_) % 3;                                              \
        const int c_ = wave + (i_) * 8;          /* chunk 0..63 */            \
        const int k_ = c_ * 32 + q * 8;                                       \
        if (k_ < 2000) {                                                      \
            _Pragma("unroll")                                                 \
            for (int rt_ = 0; rt_ < 4; ++rt_) {                               \
                const float* p_ = xr0 + rt_ * 32000 + k_;                     \
                fA[s_][rt_][0] = *(const floatx4*)p_;                         \
                fA[s_][rt_][1] = *(const floatx4*)(p_ + 4);                   \
            }                                                                 \
            fB[s_][0] = *(const floatx4*)(wr + k_);                           \
            fB[s_][1] = *(const floatx4*)(wr + k_ + 4);                       \
        } else {                                                              \
            _Pragma("unroll")                                                 \
            for (int rt_ = 0; rt_ < 4; ++rt_)                                 \
                fA[s_][rt_][0] = fA[s_][rt_][1] =                             \
                    (floatx4){0.f, 0.f, 0.f, 0.f};                            \
            fB[s_][0] = fB[s_][1] = (floatx4){0.f, 0.f, 0.f, 0.f};            \
        }                                                                     \
    }

    LOADK(0);
    LOADK(1);
#pragma unroll
    for (int i = 0; i < 8; ++i) {            // chunks wave, wave+8, ..., wave+56
        const int s = i % 3;
        shortx8 af[4];
#pragma unroll
        for (int rt = 0; rt < 4; ++rt)
            af[rt] = pk8s(fA[s][rt][0], fA[s][rt][1]);
        const shortx8 bf = pk8s(fB[s][0], fB[s][1]);
        if (i < 6) LOADK(i + 2);             // keep 2 chunks in flight
#pragma unroll
        for (int rt = 0; rt < 4; ++rt)
            acc[rt] = __builtin_amdgcn_mfma_f32_16x16x32_bf16(
                af[rt], bf, acc[rt], 0, 0, 0);
    }
#undef LOADK

    // ---- Ms prefetch (global->reg; lands during LDS epilogue) -------------
    const floatx4 msr0 = *(const floatx4*)(Mtg + t * 8);
    const floatx4 msr1 = *(const floatx4*)(Mtg + t * 8 + 4);

    // ---- per-wave partial z to LDS. C/D layout: row = q*4+v, col(h) = m --
    float* zw = zpart + wave * 1088;
#pragma unroll
    for (int rt = 0; rt < 4; ++rt)
#pragma unroll
        for (int v = 0; v < 4; ++v)
            zw[(rt * 16 + q * 4 + v) * 17 + m] = acc[rt][v];
    __syncthreads();

    // ---- 8-way reduce -> zs; publish Ms ----------------------------------
#pragma unroll
    for (int i = 0; i < 2; ++i) {
        const int idx = i * 512 + t;
        const int row = idx >> 4, hh = idx & 15;
        float s = 0.0f;
#pragma unroll
        for (int w = 0; w < 8; ++w) s += zpart[w * 1088 + row * 17 + hh];
        zs[row * 17 + hh] = s;
    }
    *(floatx4*)(Ms + t * 8)     = msr0;
    *(floatx4*)(Ms + t * 8 + 4) = msr1;
    __syncthreads();

    // ---- y = bias + M@z (fp32 VALU, r4-proven pattern) -------------------
    const int h  = t & 15;
    const int n0 = (t >> 4) * 2;            // 2 output rows per thread
    float s0 = 0.0f, s1 = 0.0f;
#pragma unroll 8
    for (int mm = 0; mm < 64; ++mm) {
        const float zv = zs[mm * 17 + h];
        s0 += Ms[mm * 64 + n0]     * zv;    // Ms[mm*64+n] = M[n][mm]
        s1 += Ms[mm * 64 + n0 + 1] * zv;
    }
    const float bv = bias[hbase + h];
    float* yp = y + (size_t)batch * 8192 + (size_t)n0 * 128 + hbase + h;
    yp[0]   = bv + s0;
    yp[128] = bv + s1;
}

extern "C" void kernel_launch(void* const* d_in, const int* in_sizes, int n_in,
                              void* d_out, int out_size, void* d_ws, size_t ws_size,
                              hipStream_t stream) {
    const float* x    = (const float*)d_in[0];   // (2048, 2000) fp32 (flat view)
    const int*   ei   = (const int*)d_in[1];     // (2, 4096)
    const float* ew   = (const float*)d_in[2];   // (4096,)
    const float* W    = (const float*)d_in[3];   // (128, 2000) fp32
    const float* bias = (const float*)d_in[4];   // (128,)
    float* y = (float*)d_out;                    // (32, 64, 128) fp32

    float* Mt = (float*)d_ws;                    // 4096 f (only ws use)

    mbuild<<<4, 256, 0, stream>>>(ei, ew, Mt);
    gcn_fused<<<256, 512, 0, stream>>>(x, W, Mt, bias, y);
}

// Round 9
// 89.887 us; speedup vs baseline: 1.0961x; 1.0961x over previous
//
#include <hip/hip_runtime.h>
#include <hip/hip_bf16.h>

#define EPSW 1e-6f

typedef __attribute__((ext_vector_type(4))) float floatx4;
typedef __attribute__((ext_vector_type(4))) unsigned int uintx4;
typedef __attribute__((ext_vector_type(8))) short shortx8;   // 8 bf16 (4 VGPRs)

// round-to-nearest-even float -> bf16 bits (finite inputs)
__device__ __forceinline__ unsigned short f2bf(float f) {
    unsigned int u = __float_as_uint(f);
    u = (u + 0x7fffu + ((u >> 16) & 1u)) >> 16;
    return (unsigned short)u;
}

__device__ __forceinline__ unsigned int pk2(float lo, float hi) {
    return (unsigned int)f2bf(lo) | ((unsigned int)f2bf(hi) << 16);
}

__device__ __forceinline__ uintx4 pk8(floatx4 a, floatx4 b) {
    uintx4 r;
    r.x = pk2(a.x, a.y); r.y = pk2(a.z, a.w);
    r.z = pk2(b.x, b.y); r.w = pk2(b.z, b.w);
    return r;
}

// ---------------------------------------------------------------------------
// gemm_mt: 260 blocks x 512 threads (8 waves). Structure == r4 (88.6 best)
// EXCEPT the pipeline:
//  (1) FULL-DEPTH PREFETCH: all 4 chunks' global loads issue up-front into 4
//      register sets (24 floatx4 = 96 VGPR staging; ~180 total, fits the
//      256-VGPR cap of an 8-wave block). The whole block tile (A 64 KB + B
//      128 KB fp32) is in flight before the first barrier; the compiler's
//      per-register vmcnt waits then bound each WRITEC. HBM latency is paid
//      ~once, not once per chunk behind a block-wide barrier.
//  (2) ONE barrier per chunk (r4 had 2): WRITEC(c+2) (reusing buf c&1) is
//      transitively ordered after all waves' compute(c) by barrier(c+1),
//      since each wave's compute(c) precedes its barrier(c+1).
//   blocks 0..255  : ks = bid&7 (K-slice of 256; round-robin dispatch
//                    clusters same-ks blocks per XCD -> W slice L2-resident),
//                    rt2 = bid>>3 (rows rt2*64..+63).
//   blocks 256..259: Mt[c][n] = (A@A)[n][c], 16 n-rows per block (r4 code).
// LDS layout per buf (24 KB): A granule (kq 0..7, row 0..63) at kq*1024 +
// rw*16; B granule (kq, h-row 0..127) at 8192 + kq*2048 + rw*16.
// Compute: wave w owns h-tile w (h = w*16+m); acc[4 row-tiles]; 8 MFMA per
// k-quad pass x 2 = 16 MFMA/chunk/wave.
// Epilogue: fp32 partials to zp[ks][row][h] (unique owner, plain stores).
// ---------------------------------------------------------------------------
__global__ __launch_bounds__(512) void gemm_mt(
        const float* __restrict__ x,
        const float* __restrict__ W,
        const int* __restrict__ ei,
        const float* __restrict__ ew,
        float* __restrict__ zp,
        float* __restrict__ Mt) {
    __shared__ __align__(16) unsigned char smem[2][24576];  // 48 KB
    const int bid = blockIdx.x;
    const int t   = threadIdx.x;

    if (bid >= 256) {
        // ---- Mt = (A@A)^T build, n-slice [bm*16, bm*16+16) (r4-proven) ----
        const int bm = bid - 256;
        float* A    = (float*)smem;            // 4096 f, A[n][k]
        float* deg  = A + 4096;
        float* dinv = deg + 64;
        if (t < 64) deg[t] = 1.0f;             // self-loop pre-added
        for (int i = t; i < 4096; i += 512) A[i] = 0.0f;
        __syncthreads();
        const int* srcp = ei;
        const int* dstp = ei + 4096;
#pragma unroll
        for (int i = 0; i < 8; ++i) {
            const int e = i * 512 + t;
            float w = ew[e];
            w = (w <= 0.0f) ? EPSW : w;
            atomicAdd(&deg[dstp[e]], w);
        }
        __syncthreads();
        if (t < 64) dinv[t] = 1.0f / sqrtf(deg[t]);
        __syncthreads();
#pragma unroll
        for (int i = 0; i < 8; ++i) {
            const int e = i * 512 + t;
            float w = ew[e];
            w = (w <= 0.0f) ? EPSW : w;
            const int s = srcp[e], d = dstp[e];
            atomicAdd(&A[d * 64 + s], dinv[s] * w * dinv[d]);
        }
        if (t < 64) atomicAdd(&A[t * 64 + t], dinv[t] * dinv[t]);
        __syncthreads();
        const int c  = t & 63;
        const int n0 = bm * 16 + (t >> 6);
        const int n1 = n0 + 8;
        float s0 = 0.0f, s1 = 0.0f;
#pragma unroll 8
        for (int k = 0; k < 64; ++k) {
            const float akc = A[k * 64 + c];
            s0 += A[n0 * 64 + k] * akc;
            s1 += A[n1 * 64 + k] * akc;
        }
        Mt[c * 64 + n0] = s0;
        Mt[c * 64 + n1] = s1;
        return;
    }

    // ---- GEMM blocks ------------------------------------------------------
    const int ks    = bid & 7;          // K-slice (XCD-clustered)
    const int rt2   = bid >> 3;         // 0..31
    const int rbase = rt2 * 64;
    const int kbase = ks * 256;

    const int wave = t >> 6, lane = t & 63;
    const int m = lane & 15, q = lane >> 4;
    const int kq = t & 7;               // staging granule col 0..7
    const int rw = t >> 3;              // staging row 0..63

    floatx4 acc[4];
#pragma unroll
    for (int rt = 0; rt < 4; ++rt) acc[rt] = (floatx4){0.f, 0.f, 0.f, 0.f};

    // 4-deep staging register sets (all indices compile-time constant)
    floatx4 sA[4][2];    // [chunk][half]       : x row rw, 32 B
    floatx4 sB[4][4];    // [chunk][2*j + half] : W rows rw, rw+64, 32 B each

#define LOADC(c)                                                              \
    {                                                                         \
        const int k_ = kbase + (c) * 64 + kq * 8;                             \
        if (k_ < 2000) {                                                      \
            const float* pa_ = x + (size_t)(rbase + rw) * 2000 + k_;          \
            const float* p0_ = W + (size_t)rw * 2000 + k_;                    \
            const float* p1_ = W + (size_t)(rw + 64) * 2000 + k_;             \
            sA[c][0] = *(const floatx4*)pa_;                                  \
            sA[c][1] = *(const floatx4*)(pa_ + 4);                            \
            sB[c][0] = *(const floatx4*)p0_;                                  \
            sB[c][1] = *(const floatx4*)(p0_ + 4);                            \
            sB[c][2] = *(const floatx4*)p1_;                                  \
            sB[c][3] = *(const floatx4*)(p1_ + 4);                            \
        } else {                                                              \
            sA[c][0] = sA[c][1] = (floatx4){0.f, 0.f, 0.f, 0.f};              \
            sB[c][0] = sB[c][1] = sB[c][2] = sB[c][3] =                       \
                (floatx4){0.f, 0.f, 0.f, 0.f};                                \
        }                                                                     \
    }

#define WRITEC(c)                                                             \
    {                                                                         \
        unsigned char* sb_ = smem[(c) & 1];                                   \
        *(uintx4*)(sb_ + kq * 1024 + rw * 16)               =                 \
            pk8(sA[c][0], sA[c][1]);                                          \
        *(uintx4*)(sb_ + 8192 + kq * 2048 + rw * 16)        =                 \
            pk8(sB[c][0], sB[c][1]);                                          \
        *(uintx4*)(sb_ + 8192 + kq * 2048 + (rw + 64) * 16) =                 \
            pk8(sB[c][2], sB[c][3]);                                          \
    }

    // issue ALL chunks' loads up-front: whole tile in flight at once
    LOADC(0);
    LOADC(1);
    LOADC(2);
    LOADC(3);

#pragma unroll
    for (int c = 0; c < 4; ++c) {
        WRITEC(c);                       // fine-grained vmcnt on set c's regs
        __syncthreads();                 // publishes buf c&1; also orders
                                         // compute(c-1) before WRITEC(c+1)'s
                                         // buffer reuse at c+2 (transitive)
        const unsigned char* sb = smem[c & 1];
#pragma unroll
        for (int p = 0; p < 2; ++p) {
            const int kgq = p * 4 + q;
            shortx8 af[4];
#pragma unroll
            for (int rt = 0; rt < 4; ++rt)
                af[rt] = *(const shortx8*)(sb + kgq * 1024 + (rt * 16 + m) * 16);
            const shortx8 bf = *(const shortx8*)(sb + 8192 + kgq * 2048 +
                                                 (wave * 16 + m) * 16);
#pragma unroll
            for (int rt = 0; rt < 4; ++rt)
                acc[rt] = __builtin_amdgcn_mfma_f32_16x16x32_bf16(
                    af[rt], bf, acc[rt], 0, 0, 0);
        }
    }
#undef LOADC
#undef WRITEC

    // epilogue: partial z. C/D layout: row = q*4+v, col = m.
    float* zslice = zp + ((size_t)ks * 2048 + rbase) * 128;
    const int h = wave * 16 + m;
#pragma unroll
    for (int rt = 0; rt < 4; ++rt) {
#pragma unroll
        for (int v = 0; v < 4; ++v) {
            const int n = rt * 16 + q * 4 + v;
            zslice[n * 128 + h] = acc[rt][v];
        }
    }
}

// ---------------------------------------------------------------------------
// apply_M: y[b][n][h] = bias[h] + sum_m M[n][m] * (sum_ks zp[ks][b*64+m][h])
// Grid (32 b, 8 h-chunks of 16) x 256 thr (r1-proven).
// ---------------------------------------------------------------------------
__global__ __launch_bounds__(256) void apply_M(const float* __restrict__ zp,
                                               const float* __restrict__ Mtg,
                                               const float* __restrict__ bias,
                                               float* __restrict__ y) {
    __shared__ float Ms[4096];
    __shared__ float zs[64][16];
    const int b  = blockIdx.x;
    const int hc = blockIdx.y;
    const int t  = threadIdx.x;
#pragma unroll
    for (int i = 0; i < 16; ++i) Ms[i * 256 + t] = Mtg[i * 256 + t];
#pragma unroll
    for (int i = 0; i < 4; ++i) {
        const int idx = i * 256 + t;
        const int mr = idx >> 4, hh = idx & 15;
        float s = 0.0f;
#pragma unroll
        for (int ks = 0; ks < 8; ++ks)
            s += zp[((size_t)ks * 2048 + b * 64 + mr) * 128 + hc * 16 + hh];
        zs[mr][hh] = s;
    }
    __syncthreads();
    const int h  = t & 15;
    const int n0 = (t >> 4) * 4;
    const float bv = bias[hc * 16 + h];
    float s0 = bv, s1 = bv, s2 = bv, s3 = bv;
#pragma unroll
    for (int mm = 0; mm < 64; ++mm) {
        const float zv = zs[mm][h];
        s0 += Ms[mm * 64 + n0 + 0] * zv;
        s1 += Ms[mm * 64 + n0 + 1] * zv;
        s2 += Ms[mm * 64 + n0 + 2] * zv;
        s3 += Ms[mm * 64 + n0 + 3] * zv;
    }
    float* yp = y + (size_t)b * 8192 + (size_t)n0 * 128 + hc * 16 + h;
    yp[0]   = s0;
    yp[128] = s1;
    yp[256] = s2;
    yp[384] = s3;
}

extern "C" void kernel_launch(void* const* d_in, const int* in_sizes, int n_in,
                              void* d_out, int out_size, void* d_ws, size_t ws_size,
                              hipStream_t stream) {
    const float* x    = (const float*)d_in[0];   // (2048, 2000) fp32 (flat view)
    const int*   ei   = (const int*)d_in[1];     // (2, 4096)
    const float* ew   = (const float*)d_in[2];   // (4096,)
    const float* W    = (const float*)d_in[3];   // (128, 2000) fp32
    const float* bias = (const float*)d_in[4];   // (128,)
    float* y = (float*)d_out;                    // (32, 64, 128) fp32

    float* zp = (float*)d_ws;                    // 8*2048*128 f (8 MB)
    float* Mt = zp + 2097152;                    // 4096 f

    gemm_mt<<<260, 512, 0, stream>>>(x, W, ei, ew, zp, Mt);
    apply_M<<<dim3(32, 8), 256, 0, stream>>>(zp, Mt, bias, y);
}